// Round 1
// baseline (2087.442 us; speedup 1.0000x reference)
//
#include <hip/hip_runtime.h>
#include <hip/hip_bf16.h>
#include <math.h>

#define B 2
#define S 2048
#define D 1024
#define H 16
#define DK 64

// ---------------------------------------------------------------------------
// GEMM: Y[n,m] = sum_k X[n,k] * W[m,k] (+ bias[m])      X:(N,K)  W:(M,K)
// 128x128 tile, BK=16, 256 threads, 8x8 micro-tile per thread.
// LDS k-major with +4 pad (stride 132 -> bank shift 4 per kk).
// ---------------------------------------------------------------------------
__global__ __launch_bounds__(256) void gemm_xwt_kernel(
    const float* __restrict__ X, const float* __restrict__ W,
    const float* __restrict__ bias, float* __restrict__ Y,
    int N, int K, int M)
{
    const int tid = threadIdx.x;
    const int tx = tid & 15, ty = tid >> 4;
    const int m0 = blockIdx.x * 128;
    const int n0 = blockIdx.y * 128;

    __shared__ float Xs[16][132];
    __shared__ float Ws[16][132];

    float acc[8][8];
#pragma unroll
    for (int i = 0; i < 8; ++i)
#pragma unroll
        for (int j = 0; j < 8; ++j) acc[i][j] = 0.f;

    for (int k0 = 0; k0 < K; k0 += 16) {
        __syncthreads();
#pragma unroll
        for (int it = 0; it < 2; ++it) {
            int idx = it * 256 + tid;      // 512 float4 slots per operand
            int r   = idx >> 2;            // 0..127
            int kv  = (idx & 3) * 4;       // 0,4,8,12
            const float4 vx = *(const float4*)&X[(size_t)(n0 + r) * K + k0 + kv];
            Xs[kv + 0][r] = vx.x; Xs[kv + 1][r] = vx.y;
            Xs[kv + 2][r] = vx.z; Xs[kv + 3][r] = vx.w;
            const float4 vw = *(const float4*)&W[(size_t)(m0 + r) * K + k0 + kv];
            Ws[kv + 0][r] = vw.x; Ws[kv + 1][r] = vw.y;
            Ws[kv + 2][r] = vw.z; Ws[kv + 3][r] = vw.w;
        }
        __syncthreads();
#pragma unroll
        for (int kk = 0; kk < 16; ++kk) {
            float a[8], bvals[8];
#pragma unroll
            for (int i = 0; i < 8; ++i) a[i] = Xs[kk][ty * 8 + i];
#pragma unroll
            for (int j = 0; j < 8; ++j) bvals[j] = Ws[kk][tx + 16 * j];
#pragma unroll
            for (int i = 0; i < 8; ++i)
#pragma unroll
                for (int j = 0; j < 8; ++j) acc[i][j] += a[i] * bvals[j];
        }
    }

#pragma unroll
    for (int i = 0; i < 8; ++i) {
        const int n = n0 + ty * 8 + i;
#pragma unroll
        for (int j = 0; j < 8; ++j) {
            const int m = m0 + tx + 16 * j;
            float v = acc[i][j];
            if (bias) v += bias[m];
            Y[(size_t)n * M + m] = v;
        }
    }
}

// ---------------------------------------------------------------------------
// Attention per (b, h, 64-row q-tile). 256 threads (16x16), 4x4 micro-tile,
// thread owns rows 4*ty..4*ty+3 and cols tx, tx+16, tx+32, tx+48 of each
// 64x64 tile. Pass A: scores + online (m,l), raw scores -> attn global.
// Pass B: read back, p = exp(s-m)/l, write attn, accumulate ctx = P*V.
// ---------------------------------------------------------------------------
__global__ __launch_bounds__(256) void attn_kernel(
    const float* __restrict__ Qg, const float* __restrict__ Kg,
    const float* __restrict__ Vg, const int* __restrict__ maskg,
    float* __restrict__ attn, float* __restrict__ ctx)
{
    const int tid = threadIdx.x;
    const int tx = tid & 15, ty = tid >> 4;
    const int qt = blockIdx.x;   // 0..31
    const int h  = blockIdx.y;   // 0..15
    const int b  = blockIdx.z;   // 0..1
    const int q0 = qt * 64;

    __shared__ float bufA[64][68];   // Qs (pass A) / Ps (pass B)
    __shared__ float bufB[64][68];   // Ks (pass A) / V-transposed (pass B)

    // stage Q tile once: bufA[r][c] = Q[b, q0+r, h*64+c]
#pragma unroll
    for (int it = 0; it < 4; ++it) {
        int idx = it * 256 + tid;       // 1024 float4 slots
        int r   = idx >> 4;             // 0..63
        int c4  = (idx & 15) * 4;
        const float4 v = *(const float4*)&Qg[((size_t)(b * S) + q0 + r) * D + h * DK + c4];
        bufA[r][c4 + 0] = v.x; bufA[r][c4 + 1] = v.y;
        bufA[r][c4 + 2] = v.z; bufA[r][c4 + 3] = v.w;
    }

    float m[4], l[4];
#pragma unroll
    for (int i = 0; i < 4; ++i) { m[i] = -1e30f; l[i] = 0.f; }

    const float scale = 0.125f;  // 1/sqrt(DK)
    float* attn_bh = attn + (size_t)(b * H + h) * S * S;

    // ---------------- pass A ----------------
    for (int kt = 0; kt < S / 64; ++kt) {
        const int k0 = kt * 64;
        __syncthreads();
#pragma unroll
        for (int it = 0; it < 4; ++it) {
            int idx = it * 256 + tid;
            int r   = idx >> 4;
            int c4  = (idx & 15) * 4;
            const float4 v = *(const float4*)&Kg[((size_t)(b * S) + k0 + r) * D + h * DK + c4];
            bufB[r][c4 + 0] = v.x; bufB[r][c4 + 1] = v.y;
            bufB[r][c4 + 2] = v.z; bufB[r][c4 + 3] = v.w;
        }
        __syncthreads();

        float s[4][4];
#pragma unroll
        for (int i = 0; i < 4; ++i)
#pragma unroll
            for (int j = 0; j < 4; ++j) s[i][j] = 0.f;

#pragma unroll
        for (int kq = 0; kq < 16; ++kq) {
            float4 a[4], bb[4];
#pragma unroll
            for (int i = 0; i < 4; ++i) a[i]  = *(const float4*)&bufA[4 * ty + i][4 * kq];
#pragma unroll
            for (int j = 0; j < 4; ++j) bb[j] = *(const float4*)&bufB[tx + 16 * j][4 * kq];
#pragma unroll
            for (int i = 0; i < 4; ++i)
#pragma unroll
                for (int j = 0; j < 4; ++j)
                    s[i][j] += a[i].x * bb[j].x + a[i].y * bb[j].y +
                               a[i].z * bb[j].z + a[i].w * bb[j].w;
        }

        int mv[4];
#pragma unroll
        for (int j = 0; j < 4; ++j) mv[j] = maskg[b * S + k0 + tx + 16 * j];
#pragma unroll
        for (int i = 0; i < 4; ++i)
#pragma unroll
            for (int j = 0; j < 4; ++j) {
                float v = s[i][j] * scale;
                if (mv[j] == 0) v = -1e9f;
                s[i][j] = v;
            }

        // write raw (scaled+masked) scores
#pragma unroll
        for (int i = 0; i < 4; ++i) {
            const size_t rowoff = (size_t)(q0 + 4 * ty + i) * S + k0;
#pragma unroll
            for (int j = 0; j < 4; ++j) attn_bh[rowoff + tx + 16 * j] = s[i][j];
        }

        // online max / sum (reduce across the 16 tx-lanes of this ty-group)
#pragma unroll
        for (int i = 0; i < 4; ++i) {
            float tmax = fmaxf(fmaxf(s[i][0], s[i][1]), fmaxf(s[i][2], s[i][3]));
            tmax = fmaxf(tmax, __shfl_xor(tmax, 1));
            tmax = fmaxf(tmax, __shfl_xor(tmax, 2));
            tmax = fmaxf(tmax, __shfl_xor(tmax, 4));
            tmax = fmaxf(tmax, __shfl_xor(tmax, 8));
            const float nm = fmaxf(m[i], tmax);
            float tsum = expf(s[i][0] - nm) + expf(s[i][1] - nm) +
                         expf(s[i][2] - nm) + expf(s[i][3] - nm);
            tsum += __shfl_xor(tsum, 1);
            tsum += __shfl_xor(tsum, 2);
            tsum += __shfl_xor(tsum, 4);
            tsum += __shfl_xor(tsum, 8);
            l[i] = l[i] * expf(m[i] - nm) + tsum;
            m[i] = nm;
        }
    }

    float inv_l[4];
#pragma unroll
    for (int i = 0; i < 4; ++i) inv_l[i] = 1.f / l[i];

    float cacc[4][4];
#pragma unroll
    for (int i = 0; i < 4; ++i)
#pragma unroll
        for (int j = 0; j < 4; ++j) cacc[i][j] = 0.f;

    // ---------------- pass B ----------------
    for (int kt = 0; kt < S / 64; ++kt) {
        const int k0 = kt * 64;
        __syncthreads();   // all pass-A reads of bufA/bufB done; prev iter reads done
        // V tile transposed: bufB[c][kk] = V[b, k0+kk, h*64+c]
#pragma unroll
        for (int it = 0; it < 4; ++it) {
            int idx = it * 256 + tid;
            int kk  = idx >> 4;
            int c4  = (idx & 15) * 4;
            const float4 v = *(const float4*)&Vg[((size_t)(b * S) + k0 + kk) * D + h * DK + c4];
            bufB[c4 + 0][kk] = v.x; bufB[c4 + 1][kk] = v.y;
            bufB[c4 + 2][kk] = v.z; bufB[c4 + 3][kk] = v.w;
        }
        // finalize p for own 4x4, write attn, stash in bufA (Ps)
#pragma unroll
        for (int i = 0; i < 4; ++i) {
            const int row = 4 * ty + i;
            const size_t rowoff = (size_t)(q0 + row) * S + k0;
#pragma unroll
            for (int j = 0; j < 4; ++j) {
                const int col = tx + 16 * j;
                const float p = expf(attn_bh[rowoff + col] - m[i]) * inv_l[i];
                attn_bh[rowoff + col] = p;
                bufA[row][col] = p;
            }
        }
        __syncthreads();
#pragma unroll
        for (int kq = 0; kq < 16; ++kq) {
            float4 a[4], bb[4];
#pragma unroll
            for (int i = 0; i < 4; ++i) a[i]  = *(const float4*)&bufA[4 * ty + i][4 * kq];
#pragma unroll
            for (int j = 0; j < 4; ++j) bb[j] = *(const float4*)&bufB[tx + 16 * j][4 * kq];
#pragma unroll
            for (int i = 0; i < 4; ++i)
#pragma unroll
                for (int j = 0; j < 4; ++j)
                    cacc[i][j] += a[i].x * bb[j].x + a[i].y * bb[j].y +
                                  a[i].z * bb[j].z + a[i].w * bb[j].w;
        }
    }

    // write ctx (layout B,S,D with head-major columns)
#pragma unroll
    for (int i = 0; i < 4; ++i) {
        const size_t rowoff = ((size_t)(b * S) + q0 + 4 * ty + i) * D + h * DK;
#pragma unroll
        for (int j = 0; j < 4; ++j) ctx[rowoff + tx + 16 * j] = cacc[i][j];
    }
}

// ---------------------------------------------------------------------------
extern "C" void kernel_launch(void* const* d_in, const int* in_sizes, int n_in,
                              void* d_out, int out_size, void* d_ws, size_t ws_size,
                              hipStream_t stream)
{
    const float* query = (const float*)d_in[0];
    const float* key   = (const float*)d_in[1];
    const float* value = (const float*)d_in[2];
    const int*   mask  = (const int*)d_in[3];
    const float* w_q   = (const float*)d_in[4];
    const float* w_k   = (const float*)d_in[5];
    const float* w_v   = (const float*)d_in[6];
    const float* w_o   = (const float*)d_in[7];
    const float* b_o   = (const float*)d_in[8];

    float* out  = (float*)d_out;                       // B*S*D
    float* attn = out + (size_t)B * S * D;             // B*H*S*S

    // workspace: Q | K | V  (ctx aliases Q — each block's ctx-write region
    // equals its own Q-read region, and Q is consumed into LDS at block start)
    float* Qb = (float*)d_ws;
    float* Kb = Qb + (size_t)B * S * D;
    float* Vb = Kb + (size_t)B * S * D;
    float* Cb = Qb;

    const dim3 blk(256);
    const dim3 ggrid(D / 128, (B * S) / 128);          // (8, 32)

    gemm_xwt_kernel<<<ggrid, blk, 0, stream>>>(query, w_q, nullptr, Qb, B * S, D, D);
    gemm_xwt_kernel<<<ggrid, blk, 0, stream>>>(key,   w_k, nullptr, Kb, B * S, D, D);
    gemm_xwt_kernel<<<ggrid, blk, 0, stream>>>(value, w_v, nullptr, Vb, B * S, D, D);

    const dim3 agrid(S / 64, H, B);                    // (32, 16, 2)
    attn_kernel<<<agrid, blk, 0, stream>>>(Qb, Kb, Vb, mask, attn, Cb);

    gemm_xwt_kernel<<<ggrid, blk, 0, stream>>>(Cb, w_o, b_o, out, B * S, D, D);
}

// Round 2
// 438.363 us; speedup vs baseline: 4.7619x; 4.7619x over previous
//
#include <hip/hip_runtime.h>
#include <hip/hip_bf16.h>
#include <math.h>

#define B 2
#define S 2048
#define D 1024
#define H 16
#define DK 64

typedef __attribute__((ext_vector_type(8))) short bf8;            // 8 bf16 (MFMA frag)
typedef __attribute__((ext_vector_type(8))) unsigned short u16x8;
typedef __attribute__((ext_vector_type(4))) unsigned short u16x4;
typedef __attribute__((ext_vector_type(4))) float f32x4;

__device__ __forceinline__ float bf2f(unsigned short u) {
    union { unsigned int i; float f; } v; v.i = ((unsigned int)u) << 16; return v.f;
}
__device__ __forceinline__ unsigned short f2bf_rne(float x) {
    __hip_bfloat16 h = __float2bfloat16(x);
    union { __hip_bfloat16 h; unsigned short u; } v; v.h = h; return v.u;
}
__device__ __forceinline__ unsigned short f2bf_trunc(float x) {
    union { float f; unsigned int i; } v; v.f = x; return (unsigned short)(v.i >> 16);
}

// ---------------------------------------------------------------------------
// MFMA GEMM: Y[n][m] = sum_k X[n][k] * W[m][k]   N=4096, K=M=1024
// tile 128(n) x 64(m), BK=32, 256 thr = 4 waves (2x2), wave owns 64n x 32m.
// LDS rows 128B = [hi 32bf16 | lo 32bf16], XOR-swizzled (r&7)<<3 (ushort idx).
// SPLIT: 3-term hi/lo bf16 emulation of fp32 (drop lo*lo).
// EPI 0: fp32 + bias   EPI 1: hi/lo bf16 pair   EPI 2: transposed bf16 [B][D][S]
// ---------------------------------------------------------------------------
template<int EPI, bool SPLIT, bool INBF16>
__global__ __launch_bounds__(256) void gemm_mfma(
    const void* __restrict__ Xv, const float* __restrict__ W,
    const float* __restrict__ bias,
    void* __restrict__ Y0v, void* __restrict__ Y1v)
{
    const int tid  = threadIdx.x;
    const int lane = tid & 63;
    const int w    = tid >> 6;
    const int wn   = w >> 1, wm = w & 1;
    const int m0   = blockIdx.x * 64;
    const int n0   = blockIdx.y * 128;

    __shared__ __align__(16) unsigned short Xs[128 * 64];
    __shared__ __align__(16) unsigned short Ws[64 * 64];

    f32x4 acc[4][2];
#pragma unroll
    for (int s = 0; s < 4; ++s)
#pragma unroll
        for (int t = 0; t < 2; ++t) acc[s][t] = (f32x4){0.f, 0.f, 0.f, 0.f};

    const float*          Xf = (const float*)Xv;
    const unsigned short* Xb = (const unsigned short*)Xv;
    const int kg = (lane >> 4) * 8;

    for (int k0 = 0; k0 < 1024; k0 += 32) {
        __syncthreads();
        if (INBF16) {
#pragma unroll
            for (int i = 0; i < 2; ++i) {
                int cid = i * 256 + tid;
                int r = cid >> 2, c = (cid & 3) * 8;
                u16x8 v = *(const u16x8*)&Xb[(size_t)(n0 + r) * 1024 + k0 + c];
                *(u16x8*)&Xs[r * 64 + (c ^ ((r & 7) << 3))] = v;
            }
        } else {
#pragma unroll
            for (int i = 0; i < 4; ++i) {
                int cid = i * 256 + tid;
                int r = cid >> 3, c = (cid & 7) * 4;
                float4 v = *(const float4*)&Xf[(size_t)(n0 + r) * 1024 + k0 + c];
                float vv[4] = {v.x, v.y, v.z, v.w};
                u16x4 hi, lo;
#pragma unroll
                for (int j = 0; j < 4; ++j) hi[j] = f2bf_trunc(vv[j]);
                *(u16x4*)&Xs[r * 64 + (c ^ ((r & 7) << 3))] = hi;
                if (SPLIT) {
#pragma unroll
                    for (int j = 0; j < 4; ++j) lo[j] = f2bf_rne(vv[j] - bf2f(hi[j]));
                    *(u16x4*)&Xs[r * 64 + ((32 + c) ^ ((r & 7) << 3))] = lo;
                }
            }
        }
#pragma unroll
        for (int i = 0; i < 2; ++i) {
            int cid = i * 256 + tid;
            int r = cid >> 3, c = (cid & 7) * 4;
            float4 v = *(const float4*)&W[(size_t)(m0 + r) * 1024 + k0 + c];
            float vv[4] = {v.x, v.y, v.z, v.w};
            u16x4 hi, lo;
#pragma unroll
            for (int j = 0; j < 4; ++j) hi[j] = f2bf_trunc(vv[j]);
            *(u16x4*)&Ws[r * 64 + (c ^ ((r & 7) << 3))] = hi;
            if (SPLIT) {
#pragma unroll
                for (int j = 0; j < 4; ++j) lo[j] = f2bf_rne(vv[j] - bf2f(hi[j]));
                *(u16x4*)&Ws[r * 64 + ((32 + c) ^ ((r & 7) << 3))] = lo;
            }
        }
        __syncthreads();

        bf8 ah[4], al[4], bh[2], bl[2];
#pragma unroll
        for (int s = 0; s < 4; ++s) {
            int r = wn * 64 + s * 16 + (lane & 15);
            ah[s] = *(const bf8*)&Xs[r * 64 + (kg ^ ((r & 7) << 3))];
            if (SPLIT) al[s] = *(const bf8*)&Xs[r * 64 + ((32 + kg) ^ ((r & 7) << 3))];
        }
#pragma unroll
        for (int t = 0; t < 2; ++t) {
            int r = wm * 32 + t * 16 + (lane & 15);
            bh[t] = *(const bf8*)&Ws[r * 64 + (kg ^ ((r & 7) << 3))];
            if (SPLIT) bl[t] = *(const bf8*)&Ws[r * 64 + ((32 + kg) ^ ((r & 7) << 3))];
        }
#pragma unroll
        for (int s = 0; s < 4; ++s)
#pragma unroll
            for (int t = 0; t < 2; ++t) {
                acc[s][t] = __builtin_amdgcn_mfma_f32_16x16x32_bf16(ah[s], bh[t], acc[s][t], 0, 0, 0);
                if (SPLIT) {
                    acc[s][t] = __builtin_amdgcn_mfma_f32_16x16x32_bf16(ah[s], bl[t], acc[s][t], 0, 0, 0);
                    acc[s][t] = __builtin_amdgcn_mfma_f32_16x16x32_bf16(al[s], bh[t], acc[s][t], 0, 0, 0);
                }
            }
    }

#pragma unroll
    for (int s = 0; s < 4; ++s)
#pragma unroll
        for (int t = 0; t < 2; ++t) {
            const int nb = n0 + wn * 64 + 16 * s + 4 * (lane >> 4);
            const int m  = m0 + wm * 32 + 16 * t + (lane & 15);
            if (EPI == 0) {
                float* Y = (float*)Y0v;
                const float bb = bias ? bias[m] : 0.f;
#pragma unroll
                for (int r = 0; r < 4; ++r)
                    Y[(size_t)(nb + r) * 1024 + m] = acc[s][t][r] + bb;
            } else if (EPI == 1) {
                unsigned short* Yh = (unsigned short*)Y0v;
                unsigned short* Yl = (unsigned short*)Y1v;
#pragma unroll
                for (int r = 0; r < 4; ++r) {
                    float v = acc[s][t][r];
                    unsigned short hi = f2bf_trunc(v);
                    Yh[(size_t)(nb + r) * 1024 + m] = hi;
                    Yl[(size_t)(nb + r) * 1024 + m] = f2bf_rne(v - bf2f(hi));
                }
            } else {
                unsigned short* Vt = (unsigned short*)Y0v;
                u16x4 pk;
#pragma unroll
                for (int r = 0; r < 4; ++r) pk[r] = f2bf_rne(acc[s][t][r]);
                size_t addr = ((size_t)(nb >> 11) * 1024 + m) * 2048 + (nb & 2047);
                *(u16x4*)&Vt[addr] = pk;
            }
        }
}

// ---------------------------------------------------------------------------
// bf16 global (row-major, srcStride) -> swizzled LDS tile [64][64 ushort]
// ---------------------------------------------------------------------------
__device__ __forceinline__ void stage_tile(unsigned short* dst,
                                           const unsigned short* src,
                                           int srcStride, int tid)
{
#pragma unroll
    for (int i = 0; i < 2; ++i) {
        int cid = i * 256 + tid;
        int r = cid >> 3, c = (cid & 7) * 8;
        u16x8 v = *(const u16x8*)&src[(size_t)r * srcStride + c];
        *(u16x8*)&dst[r * 64 + (c ^ ((r & 7) << 3))] = v;
    }
}

// ---------------------------------------------------------------------------
// Attention per (b, h, 64-q-tile). 4 waves, wave owns 16 q rows.
// Swapped MFMA: S^T[key][q] = mfma(K_frag, Q_frag) -> lane owns column q=lane&15.
// Pass A: hi-only scores -> online (m,l). Pass B: split scores -> p (exact m,l
// known) -> bf16 P via wave-private LDS -> coalesced fp32 attn store + PV MFMA.
// ---------------------------------------------------------------------------
__global__ __launch_bounds__(256) void attn_mfma(
    const unsigned short* __restrict__ Qh, const unsigned short* __restrict__ Ql,
    const unsigned short* __restrict__ Kh, const unsigned short* __restrict__ Kl,
    const unsigned short* __restrict__ Vt, const int* __restrict__ maskg,
    float* __restrict__ attn, unsigned short* __restrict__ ctx)
{
    const int tid  = threadIdx.x;
    const int lane = tid & 63;
    const int w    = tid >> 6;
    const int qt = blockIdx.x, h = blockIdx.y, b = blockIdx.z;
    const int q0 = qt * 64;

    __shared__ __align__(16) unsigned short Khs[4096];
    __shared__ __align__(16) unsigned short Kls[4096];
    __shared__ __align__(16) unsigned short Vts[4096];
    __shared__ __align__(16) unsigned short Pus[4][1024];
    __shared__ float biasS[64];

    const int kg = (lane >> 4) * 8;
    const int q  = lane & 15;                  // this lane's q column (in wave)
    const int qrow = q0 + w * 16 + q;

    bf8 qh[2], ql[2];
    {
        const unsigned short* p1 = Qh + (size_t)(b * S + qrow) * D + h * DK + kg;
        qh[0] = *(const bf8*)p1; qh[1] = *(const bf8*)(p1 + 32);
        const unsigned short* p2 = Ql + (size_t)(b * S + qrow) * D + h * DK + kg;
        ql[0] = *(const bf8*)p2; ql[1] = *(const bf8*)(p2 + 32);
    }

    const float scale = 0.125f;                // 1/sqrt(DK)
    float mrow = -1e30f, lrow = 0.f;

    // ---------------- pass A: online max/sum (hi-only precision) ----------
    for (int kt = 0; kt < S / 64; ++kt) {
        const int k0 = kt * 64;
        __syncthreads();
        stage_tile(Khs, Kh + (size_t)(b * S + k0) * D + h * DK, D, tid);
        if (tid < 64) biasS[tid] = maskg[b * S + k0 + tid] ? 0.f : -1e9f;
        __syncthreads();

        f32x4 sacc[4];
#pragma unroll
        for (int st = 0; st < 4; ++st) sacc[st] = (f32x4){0.f, 0.f, 0.f, 0.f};
#pragma unroll
        for (int st = 0; st < 4; ++st) {
            int r = st * 16 + q;
#pragma unroll
            for (int dh = 0; dh < 2; ++dh) {
                bf8 kf = *(const bf8*)&Khs[r * 64 + ((dh * 32 + kg) ^ ((r & 7) << 3))];
                sacc[st] = __builtin_amdgcn_mfma_f32_16x16x32_bf16(kf, qh[dh], sacc[st], 0, 0, 0);
            }
        }
        float sc[16];
        float tmax = -1e30f;
#pragma unroll
        for (int st = 0; st < 4; ++st)
#pragma unroll
            for (int rr = 0; rr < 4; ++rr) {
                float v = sacc[st][rr] * scale + biasS[st * 16 + (lane >> 4) * 4 + rr];
                sc[st * 4 + rr] = v;
                tmax = fmaxf(tmax, v);
            }
        tmax = fmaxf(tmax, __shfl_xor(tmax, 16));
        tmax = fmaxf(tmax, __shfl_xor(tmax, 32));
        const float nm = fmaxf(mrow, tmax);
        float ts = 0.f;
#pragma unroll
        for (int i = 0; i < 16; ++i) ts += __expf(sc[i] - nm);
        ts += __shfl_xor(ts, 16);
        ts += __shfl_xor(ts, 32);
        lrow = lrow * __expf(mrow - nm) + ts;
        mrow = nm;
    }
    const float inv_l = 1.f / lrow;

    // ---------------- pass B: split scores -> p, attn store, PV ------------
    f32x4 cacc[4];
#pragma unroll
    for (int dt = 0; dt < 4; ++dt) cacc[dt] = (f32x4){0.f, 0.f, 0.f, 0.f};
    float* attn_bh = attn + (size_t)(b * H + h) * S * S;

    for (int kt = 0; kt < S / 64; ++kt) {
        const int k0 = kt * 64;
        __syncthreads();
        stage_tile(Khs, Kh + (size_t)(b * S + k0) * D + h * DK, D, tid);
        stage_tile(Kls, Kl + (size_t)(b * S + k0) * D + h * DK, D, tid);
        stage_tile(Vts, Vt + ((size_t)(b * 1024 + h * DK)) * 2048 + k0, 2048, tid);
        if (tid < 64) biasS[tid] = maskg[b * S + k0 + tid] ? 0.f : -1e9f;
        __syncthreads();

        f32x4 sacc[4];
#pragma unroll
        for (int st = 0; st < 4; ++st) sacc[st] = (f32x4){0.f, 0.f, 0.f, 0.f};
#pragma unroll
        for (int st = 0; st < 4; ++st) {
            int r = st * 16 + q;
#pragma unroll
            for (int dh = 0; dh < 2; ++dh) {
                bf8 kf = *(const bf8*)&Khs[r * 64 + ((dh * 32 + kg) ^ ((r & 7) << 3))];
                bf8 lf = *(const bf8*)&Kls[r * 64 + ((dh * 32 + kg) ^ ((r & 7) << 3))];
                sacc[st] = __builtin_amdgcn_mfma_f32_16x16x32_bf16(kf, qh[dh], sacc[st], 0, 0, 0);
                sacc[st] = __builtin_amdgcn_mfma_f32_16x16x32_bf16(kf, ql[dh], sacc[st], 0, 0, 0);
                sacc[st] = __builtin_amdgcn_mfma_f32_16x16x32_bf16(lf, qh[dh], sacc[st], 0, 0, 0);
            }
        }
        // p = exp(s - m) / l  (m, l final from pass A; bf16-pack into LDS)
#pragma unroll
        for (int st = 0; st < 4; ++st)
#pragma unroll
            for (int rp = 0; rp < 2; ++rp) {
                int key = st * 16 + (lane >> 4) * 4 + rp * 2;
                float p0 = __expf(sacc[st][rp * 2]     * scale + biasS[key]     - mrow) * inv_l;
                float p1 = __expf(sacc[st][rp * 2 + 1] * scale + biasS[key + 1] - mrow) * inv_l;
                unsigned int pk = (unsigned int)f2bf_rne(p0) | ((unsigned int)f2bf_rne(p1) << 16);
                *(unsigned int*)&Pus[w][q * 64 + (key ^ ((q & 7) << 3))] = pk;
            }
        // coalesced fp32 attn store (lane -> row lane>>2, 16-key chunk)
        {
            const int rq = lane >> 2;
            const int kc = (lane & 3) * 16;
            u16x8 v0 = *(const u16x8*)&Pus[w][rq * 64 + ((kc)     ^ ((rq & 7) << 3))];
            u16x8 v1 = *(const u16x8*)&Pus[w][rq * 64 + ((kc + 8) ^ ((rq & 7) << 3))];
            float* dst = attn_bh + (size_t)(q0 + w * 16 + rq) * S + k0 + kc;
            float4 f0 = {bf2f(v0[0]), bf2f(v0[1]), bf2f(v0[2]), bf2f(v0[3])};
            float4 f1 = {bf2f(v0[4]), bf2f(v0[5]), bf2f(v0[6]), bf2f(v0[7])};
            float4 f2 = {bf2f(v1[0]), bf2f(v1[1]), bf2f(v1[2]), bf2f(v1[3])};
            float4 f3 = {bf2f(v1[4]), bf2f(v1[5]), bf2f(v1[6]), bf2f(v1[7])};
            *(float4*)(dst + 0)  = f0;
            *(float4*)(dst + 4)  = f1;
            *(float4*)(dst + 8)  = f2;
            *(float4*)(dst + 12) = f3;
        }
        // PV: ctx[q][d] += P * V
        bf8 pa[2];
        pa[0] = *(const bf8*)&Pus[w][q * 64 + ((kg)      ^ ((q & 7) << 3))];
        pa[1] = *(const bf8*)&Pus[w][q * 64 + ((32 + kg) ^ ((q & 7) << 3))];
#pragma unroll
        for (int dt = 0; dt < 4; ++dt) {
            int r = dt * 16 + q;
#pragma unroll
            for (int kc2 = 0; kc2 < 2; ++kc2) {
                bf8 vf = *(const bf8*)&Vts[r * 64 + ((kc2 * 32 + kg) ^ ((r & 7) << 3))];
                cacc[dt] = __builtin_amdgcn_mfma_f32_16x16x32_bf16(pa[kc2], vf, cacc[dt], 0, 0, 0);
            }
        }
    }

    // ctx (bf16, layout [B*S][D] head-major cols)
#pragma unroll
    for (int dt = 0; dt < 4; ++dt)
#pragma unroll
        for (int rr = 0; rr < 4; ++rr) {
            int qq = q0 + w * 16 + 4 * (lane >> 4) + rr;
            ctx[(size_t)(b * S + qq) * D + h * DK + dt * 16 + (lane & 15)] =
                f2bf_rne(cacc[dt][rr]);
        }
}

// ---------------------------------------------------------------------------
extern "C" void kernel_launch(void* const* d_in, const int* in_sizes, int n_in,
                              void* d_out, int out_size, void* d_ws, size_t ws_size,
                              hipStream_t stream)
{
    const float* query = (const float*)d_in[0];
    const float* key   = (const float*)d_in[1];
    const float* value = (const float*)d_in[2];
    const int*   mask  = (const int*)d_in[3];
    const float* w_q   = (const float*)d_in[4];
    const float* w_k   = (const float*)d_in[5];
    const float* w_v   = (const float*)d_in[6];
    const float* w_o   = (const float*)d_in[7];
    const float* b_o   = (const float*)d_in[8];

    float* out  = (float*)d_out;                       // B*S*D
    float* attn = out + (size_t)B * S * D;             // B*H*S*S

    const size_t NE = (size_t)B * S * D;               // 4M elements
    unsigned short* Qh = (unsigned short*)d_ws;
    unsigned short* Ql = Qh + NE;
    unsigned short* Kh = Ql + NE;
    unsigned short* Kl = Kh + NE;
    unsigned short* Vt = Kl + NE;                      // [B][D][S] bf16
    unsigned short* Cb = Vt + NE;                      // ctx bf16

    const dim3 blk(256);
    const dim3 ggrid(D / 64, (B * S) / 128);           // (16, 32)

    gemm_mfma<1, true,  false><<<ggrid, blk, 0, stream>>>(query, w_q, nullptr, Qh, Ql);
    gemm_mfma<1, true,  false><<<ggrid, blk, 0, stream>>>(key,   w_k, nullptr, Kh, Kl);
    gemm_mfma<2, false, false><<<ggrid, blk, 0, stream>>>(value, w_v, nullptr, Vt, nullptr);

    const dim3 agrid(S / 64, H, B);                    // (32, 16, 2)
    attn_mfma<<<agrid, blk, 0, stream>>>(Qh, Ql, Kh, Kl, Vt, mask, attn, Cb);

    gemm_mfma<0, false, true><<<ggrid, blk, 0, stream>>>(Cb, w_o, b_o, out, nullptr);
}

// Round 3
// 398.962 us; speedup vs baseline: 5.2322x; 1.0988x over previous
//
#include <hip/hip_runtime.h>
#include <hip/hip_bf16.h>
#include <math.h>

#define B 2
#define S 2048
#define D 1024
#define H 16
#define DK 64

typedef __attribute__((ext_vector_type(8))) short bf8;            // 8 bf16 (MFMA frag)
typedef __attribute__((ext_vector_type(8))) unsigned short u16x8;
typedef __attribute__((ext_vector_type(4))) unsigned short u16x4;
typedef __attribute__((ext_vector_type(4))) float f32x4;

__device__ __forceinline__ float bf2f(unsigned short u) {
    union { unsigned int i; float f; } v; v.i = ((unsigned int)u) << 16; return v.f;
}
__device__ __forceinline__ unsigned short f2bf_rne(float x) {
    __hip_bfloat16 h = __float2bfloat16(x);
    union { __hip_bfloat16 h; unsigned short u; } v; v.h = h; return v.u;
}
__device__ __forceinline__ unsigned short f2bf_trunc(float x) {
    union { float f; unsigned int i; } v; v.f = x; return (unsigned short)(v.i >> 16);
}

// async global->LDS, 16B per lane. LDS dest = wave-uniform base + lane*16.
__device__ __forceinline__ void gl16(const void* g, void* l) {
    __builtin_amdgcn_global_load_lds(
        (const __attribute__((address_space(1))) void*)g,
        (__attribute__((address_space(3))) void*)l, 16, 0, 0);
}

// ---------------------------------------------------------------------------
// Pre-convert fp32 -> bf16 hi(+lo). Plain row-major outputs.
// ---------------------------------------------------------------------------
__global__ __launch_bounds__(256) void conv_split_k(
    const float* __restrict__ X, unsigned short* __restrict__ Oh,
    unsigned short* __restrict__ Ol, int n8)
{
    int t = blockIdx.x * 256 + threadIdx.x;
    if (t >= n8) return;
    const float4* s4 = (const float4*)X + (size_t)t * 2;
    float4 a = s4[0], c = s4[1];
    float v[8] = {a.x, a.y, a.z, a.w, c.x, c.y, c.z, c.w};
    u16x8 hi, lo;
#pragma unroll
    for (int j = 0; j < 8; ++j) {
        hi[j] = f2bf_trunc(v[j]);
        lo[j] = f2bf_rne(v[j] - bf2f(hi[j]));
    }
    *(u16x8*)&Oh[(size_t)t * 8] = hi;
    *(u16x8*)&Ol[(size_t)t * 8] = lo;
}

__global__ __launch_bounds__(256) void conv_hi_k(
    const float* __restrict__ X, unsigned short* __restrict__ Oh, int n8)
{
    int t = blockIdx.x * 256 + threadIdx.x;
    if (t >= n8) return;
    const float4* s4 = (const float4*)X + (size_t)t * 2;
    float4 a = s4[0], c = s4[1];
    float v[8] = {a.x, a.y, a.z, a.w, c.x, c.y, c.z, c.w};
    u16x8 hi;
#pragma unroll
    for (int j = 0; j < 8; ++j) hi[j] = f2bf_trunc(v[j]);
    *(u16x8*)&Oh[(size_t)t * 8] = hi;
}

// ---------------------------------------------------------------------------
// Fast GEMM on preconverted bf16: Y[n][m] = sum_k X[n][k]*W[m][k]
// tile 128n x 64m, 256 thr / 4 waves (2x2). LDS rows = 64 ushort (128B),
// chunk-XOR swizzle via pre-swizzled global source + linear LDS + gl16.
// SPLIT: BK=32, row=[hi32|lo32], 3-term emulation. !SPLIT: BK=64 plain hi.
// EPI 0: fp32+bias  EPI 1: hi/lo pair  EPI 2: transposed bf16 [B][D][S]
// ---------------------------------------------------------------------------
template<bool SPLIT, int EPI>
__global__ __launch_bounds__(256) void gemm_bf(
    const unsigned short* __restrict__ Xh, const unsigned short* __restrict__ Xl,
    const unsigned short* __restrict__ Wh, const unsigned short* __restrict__ Wl,
    const float* __restrict__ bias, void* __restrict__ Y0v, void* __restrict__ Y1v)
{
    const int tid  = threadIdx.x;
    const int lane = tid & 63;
    const int w    = tid >> 6;
    const int wn   = w >> 1, wm = w & 1;
    const int m0   = blockIdx.x * 64;
    const int n0   = blockIdx.y * 128;

    __shared__ __align__(16) unsigned short Xs[128 * 64];
    __shared__ __align__(16) unsigned short Ws[64 * 64];

    f32x4 acc[4][2];
#pragma unroll
    for (int s = 0; s < 4; ++s)
#pragma unroll
        for (int t = 0; t < 2; ++t) acc[s][t] = (f32x4){0.f, 0.f, 0.f, 0.f};

    const int kg    = (lane >> 4) * 8;
    const int rbase = w * 8 + (lane >> 3);
    const int jd    = lane & 7;
    const int kSteps = SPLIT ? 32 : 16;

    for (int ks = 0; ks < kSteps; ++ks) {
        __syncthreads();
#pragma unroll
        for (int i = 0; i < 4; ++i) {
            int rd = i * 32 + rbase;
            int jo = jd ^ (rd & 7);
            const unsigned short* src;
            if (SPLIT)
                src = (jo < 4) ? Xh + (size_t)(n0 + rd) * 1024 + ks * 32 + jo * 8
                               : Xl + (size_t)(n0 + rd) * 1024 + ks * 32 + (jo - 4) * 8;
            else
                src = Xh + (size_t)(n0 + rd) * 1024 + ks * 64 + jo * 8;
            gl16(src, &Xs[(i * 32 + w * 8) * 64]);
        }
#pragma unroll
        for (int i = 0; i < 2; ++i) {
            int rd = i * 32 + rbase;
            int jo = jd ^ (rd & 7);
            const unsigned short* src;
            if (SPLIT)
                src = (jo < 4) ? Wh + (size_t)(m0 + rd) * 1024 + ks * 32 + jo * 8
                               : Wl + (size_t)(m0 + rd) * 1024 + ks * 32 + (jo - 4) * 8;
            else
                src = Wh + (size_t)(m0 + rd) * 1024 + ks * 64 + jo * 8;
            gl16(src, &Ws[(i * 32 + w * 8) * 64]);
        }
        __syncthreads();

        bf8 a0[4], a1[4], b0[2], b1[2];
#pragma unroll
        for (int s = 0; s < 4; ++s) {
            int r = wn * 64 + s * 16 + (lane & 15);
            a0[s] = *(const bf8*)&Xs[r * 64 + (kg ^ ((r & 7) << 3))];
            a1[s] = *(const bf8*)&Xs[r * 64 + ((32 + kg) ^ ((r & 7) << 3))];
        }
#pragma unroll
        for (int t = 0; t < 2; ++t) {
            int r = wm * 32 + t * 16 + (lane & 15);
            b0[t] = *(const bf8*)&Ws[r * 64 + (kg ^ ((r & 7) << 3))];
            b1[t] = *(const bf8*)&Ws[r * 64 + ((32 + kg) ^ ((r & 7) << 3))];
        }
#pragma unroll
        for (int s = 0; s < 4; ++s)
#pragma unroll
            for (int t = 0; t < 2; ++t) {
                acc[s][t] = __builtin_amdgcn_mfma_f32_16x16x32_bf16(a0[s], b0[t], acc[s][t], 0, 0, 0);
                if (SPLIT) {
                    acc[s][t] = __builtin_amdgcn_mfma_f32_16x16x32_bf16(a0[s], b1[t], acc[s][t], 0, 0, 0);
                    acc[s][t] = __builtin_amdgcn_mfma_f32_16x16x32_bf16(a1[s], b0[t], acc[s][t], 0, 0, 0);
                } else {
                    acc[s][t] = __builtin_amdgcn_mfma_f32_16x16x32_bf16(a1[s], b1[t], acc[s][t], 0, 0, 0);
                }
            }
    }

#pragma unroll
    for (int s = 0; s < 4; ++s)
#pragma unroll
        for (int t = 0; t < 2; ++t) {
            const int nb = n0 + wn * 64 + 16 * s + 4 * (lane >> 4);
            const int m  = m0 + wm * 32 + 16 * t + (lane & 15);
            if (EPI == 0) {
                float* Y = (float*)Y0v;
                const float bb = bias ? bias[m] : 0.f;
#pragma unroll
                for (int r = 0; r < 4; ++r)
                    Y[(size_t)(nb + r) * 1024 + m] = acc[s][t][r] + bb;
            } else if (EPI == 1) {
                unsigned short* Yh = (unsigned short*)Y0v;
                unsigned short* Yl = (unsigned short*)Y1v;
#pragma unroll
                for (int r = 0; r < 4; ++r) {
                    float v = acc[s][t][r];
                    unsigned short hi = f2bf_trunc(v);
                    Yh[(size_t)(nb + r) * 1024 + m] = hi;
                    Yl[(size_t)(nb + r) * 1024 + m] = f2bf_rne(v - bf2f(hi));
                }
            } else {
                unsigned short* Vt = (unsigned short*)Y0v;
                u16x4 pk;
#pragma unroll
                for (int r = 0; r < 4; ++r) pk[r] = f2bf_rne(acc[s][t][r]);
                size_t addr = ((size_t)(nb >> 11) * 1024 + m) * 2048 + (nb & 2047);
                *(u16x4*)&Vt[addr] = pk;
            }
        }
}

// ---------------------------------------------------------------------------
// Round-2 verified GEMM (in-kernel fp32->hi/lo conversion). Fallback path.
// ---------------------------------------------------------------------------
template<int EPI, bool SPLIT, bool INBF16>
__global__ __launch_bounds__(256) void gemm_mfma(
    const void* __restrict__ Xv, const float* __restrict__ W,
    const float* __restrict__ bias,
    void* __restrict__ Y0v, void* __restrict__ Y1v)
{
    const int tid  = threadIdx.x;
    const int lane = tid & 63;
    const int w    = tid >> 6;
    const int wn   = w >> 1, wm = w & 1;
    const int m0   = blockIdx.x * 64;
    const int n0   = blockIdx.y * 128;

    __shared__ __align__(16) unsigned short Xs[128 * 64];
    __shared__ __align__(16) unsigned short Ws[64 * 64];

    f32x4 acc[4][2];
#pragma unroll
    for (int s = 0; s < 4; ++s)
#pragma unroll
        for (int t = 0; t < 2; ++t) acc[s][t] = (f32x4){0.f, 0.f, 0.f, 0.f};

    const float*          Xf = (const float*)Xv;
    const unsigned short* Xb = (const unsigned short*)Xv;
    const int kg = (lane >> 4) * 8;

    for (int k0 = 0; k0 < 1024; k0 += 32) {
        __syncthreads();
        if (INBF16) {
#pragma unroll
            for (int i = 0; i < 2; ++i) {
                int cid = i * 256 + tid;
                int r = cid >> 2, c = (cid & 3) * 8;
                u16x8 v = *(const u16x8*)&Xb[(size_t)(n0 + r) * 1024 + k0 + c];
                *(u16x8*)&Xs[r * 64 + (c ^ ((r & 7) << 3))] = v;
            }
        } else {
#pragma unroll
            for (int i = 0; i < 4; ++i) {
                int cid = i * 256 + tid;
                int r = cid >> 3, c = (cid & 7) * 4;
                float4 v = *(const float4*)&Xf[(size_t)(n0 + r) * 1024 + k0 + c];
                float vv[4] = {v.x, v.y, v.z, v.w};
                u16x4 hi, lo;
#pragma unroll
                for (int j = 0; j < 4; ++j) hi[j] = f2bf_trunc(vv[j]);
                *(u16x4*)&Xs[r * 64 + (c ^ ((r & 7) << 3))] = hi;
                if (SPLIT) {
#pragma unroll
                    for (int j = 0; j < 4; ++j) lo[j] = f2bf_rne(vv[j] - bf2f(hi[j]));
                    *(u16x4*)&Xs[r * 64 + ((32 + c) ^ ((r & 7) << 3))] = lo;
                }
            }
        }
#pragma unroll
        for (int i = 0; i < 2; ++i) {
            int cid = i * 256 + tid;
            int r = cid >> 3, c = (cid & 7) * 4;
            float4 v = *(const float4*)&W[(size_t)(m0 + r) * 1024 + k0 + c];
            float vv[4] = {v.x, v.y, v.z, v.w};
            u16x4 hi, lo;
#pragma unroll
            for (int j = 0; j < 4; ++j) hi[j] = f2bf_trunc(vv[j]);
            *(u16x4*)&Ws[r * 64 + (c ^ ((r & 7) << 3))] = hi;
            if (SPLIT) {
#pragma unroll
                for (int j = 0; j < 4; ++j) lo[j] = f2bf_rne(vv[j] - bf2f(hi[j]));
                *(u16x4*)&Ws[r * 64 + ((32 + c) ^ ((r & 7) << 3))] = lo;
            }
        }
        __syncthreads();

        bf8 ah[4], al[4], bh[2], bl[2];
#pragma unroll
        for (int s = 0; s < 4; ++s) {
            int r = wn * 64 + s * 16 + (lane & 15);
            ah[s] = *(const bf8*)&Xs[r * 64 + (kg ^ ((r & 7) << 3))];
            if (SPLIT) al[s] = *(const bf8*)&Xs[r * 64 + ((32 + kg) ^ ((r & 7) << 3))];
        }
#pragma unroll
        for (int t = 0; t < 2; ++t) {
            int r = wm * 32 + t * 16 + (lane & 15);
            bh[t] = *(const bf8*)&Ws[r * 64 + (kg ^ ((r & 7) << 3))];
            if (SPLIT) bl[t] = *(const bf8*)&Ws[r * 64 + ((32 + kg) ^ ((r & 7) << 3))];
        }
#pragma unroll
        for (int s = 0; s < 4; ++s)
#pragma unroll
            for (int t = 0; t < 2; ++t) {
                acc[s][t] = __builtin_amdgcn_mfma_f32_16x16x32_bf16(ah[s], bh[t], acc[s][t], 0, 0, 0);
                if (SPLIT) {
                    acc[s][t] = __builtin_amdgcn_mfma_f32_16x16x32_bf16(ah[s], bl[t], acc[s][t], 0, 0, 0);
                    acc[s][t] = __builtin_amdgcn_mfma_f32_16x16x32_bf16(al[s], bh[t], acc[s][t], 0, 0, 0);
                }
            }
    }

#pragma unroll
    for (int s = 0; s < 4; ++s)
#pragma unroll
        for (int t = 0; t < 2; ++t) {
            const int nb = n0 + wn * 64 + 16 * s + 4 * (lane >> 4);
            const int m  = m0 + wm * 32 + 16 * t + (lane & 15);
            if (EPI == 0) {
                float* Y = (float*)Y0v;
                const float bb = bias ? bias[m] : 0.f;
#pragma unroll
                for (int r = 0; r < 4; ++r)
                    Y[(size_t)(nb + r) * 1024 + m] = acc[s][t][r] + bb;
            } else if (EPI == 1) {
                unsigned short* Yh = (unsigned short*)Y0v;
                unsigned short* Yl = (unsigned short*)Y1v;
#pragma unroll
                for (int r = 0; r < 4; ++r) {
                    float v = acc[s][t][r];
                    unsigned short hi = f2bf_trunc(v);
                    Yh[(size_t)(nb + r) * 1024 + m] = hi;
                    Yl[(size_t)(nb + r) * 1024 + m] = f2bf_rne(v - bf2f(hi));
                }
            } else {
                unsigned short* Vt = (unsigned short*)Y0v;
                u16x4 pk;
#pragma unroll
                for (int r = 0; r < 4; ++r) pk[r] = f2bf_rne(acc[s][t][r]);
                size_t addr = ((size_t)(nb >> 11) * 1024 + m) * 2048 + (nb & 2047);
                *(u16x4*)&Vt[addr] = pk;
            }
        }
}

// ---------------------------------------------------------------------------
// Attention per (b, h, 128-q-tile). 8 waves, wave owns 16 q rows.
// Swapped MFMA: lane owns q column (lane&15). Staging via global_load_lds
// with pre-swizzled global source (LDS stays linear).
// Pass A: hi-only scores -> online (m,l). Pass B: 3-term split scores ->
// p fp32 direct store + bf16 P (wave-private LDS) -> PV MFMA.
// ---------------------------------------------------------------------------
__global__ __launch_bounds__(512) void attn_mfma2(
    const unsigned short* __restrict__ Qh, const unsigned short* __restrict__ Ql,
    const unsigned short* __restrict__ Kh, const unsigned short* __restrict__ Kl,
    const unsigned short* __restrict__ Vt, const int* __restrict__ maskg,
    float* __restrict__ attn, unsigned short* __restrict__ ctx)
{
    const int tid  = threadIdx.x;
    const int lane = tid & 63;
    const int w    = tid >> 6;                 // 0..7
    const int qt = blockIdx.x, h = blockIdx.y, b = blockIdx.z;
    const int q0 = qt * 128;

    __shared__ __align__(16) unsigned short Khs[4096];
    __shared__ __align__(16) unsigned short Kls[4096];
    __shared__ __align__(16) unsigned short Vts[4096];
    __shared__ __align__(16) unsigned short Pus[8][1024];

    const int kg = (lane >> 4) * 8;
    const int q  = lane & 15;
    const int qrow = q0 + w * 16 + q;

    // staging geometry: wave w fills rows w*8..w*8+7 (8 rows x 8 chunks)
    const int rd = w * 8 + (lane >> 3);
    const int jo = (lane & 7) ^ (rd & 7);
    const unsigned short* KhT = Kh + (size_t)(b * S) * 1024 + h * DK;
    const unsigned short* KlT = Kl + (size_t)(b * S) * 1024 + h * DK;
    const unsigned short* VtT = Vt + (size_t)(b * 1024 + h * DK) * 2048;

    bf8 qh[2], ql[2];
    {
        const unsigned short* p1 = Qh + (size_t)(b * S + qrow) * D + h * DK + kg;
        qh[0] = *(const bf8*)p1; qh[1] = *(const bf8*)(p1 + 32);
        const unsigned short* p2 = Ql + (size_t)(b * S + qrow) * D + h * DK + kg;
        ql[0] = *(const bf8*)p2; ql[1] = *(const bf8*)(p2 + 32);
    }

    const float scale = 0.125f;                // 1/sqrt(DK)
    float mrow = -1e30f, lrow = 0.f;

    // ---------------- pass A: online max/sum (hi-only precision) ----------
    for (int kt = 0; kt < S / 64; ++kt) {
        const int k0 = kt * 64;
        __syncthreads();
        gl16(KhT + (size_t)(k0 + rd) * 1024 + jo * 8, &Khs[w * 512]);
        __syncthreads();

        float bias_r[4][4];
#pragma unroll
        for (int st = 0; st < 4; ++st) {
            int4 mv = *(const int4*)&maskg[b * S + k0 + st * 16 + (lane >> 4) * 4];
            bias_r[st][0] = mv.x ? 0.f : -1e9f;
            bias_r[st][1] = mv.y ? 0.f : -1e9f;
            bias_r[st][2] = mv.z ? 0.f : -1e9f;
            bias_r[st][3] = mv.w ? 0.f : -1e9f;
        }

        f32x4 sacc[4];
#pragma unroll
        for (int st = 0; st < 4; ++st) sacc[st] = (f32x4){0.f, 0.f, 0.f, 0.f};
#pragma unroll
        for (int st = 0; st < 4; ++st) {
            int r = st * 16 + q;
#pragma unroll
            for (int dh = 0; dh < 2; ++dh) {
                bf8 kf = *(const bf8*)&Khs[r * 64 + ((dh * 32 + kg) ^ ((r & 7) << 3))];
                sacc[st] = __builtin_amdgcn_mfma_f32_16x16x32_bf16(kf, qh[dh], sacc[st], 0, 0, 0);
            }
        }
        float sc[16];
        float tmax = -1e30f;
#pragma unroll
        for (int st = 0; st < 4; ++st)
#pragma unroll
            for (int rr = 0; rr < 4; ++rr) {
                float v = sacc[st][rr] * scale + bias_r[st][rr];
                sc[st * 4 + rr] = v;
                tmax = fmaxf(tmax, v);
            }
        tmax = fmaxf(tmax, __shfl_xor(tmax, 16));
        tmax = fmaxf(tmax, __shfl_xor(tmax, 32));
        const float nm = fmaxf(mrow, tmax);
        float ts = 0.f;
#pragma unroll
        for (int i = 0; i < 16; ++i) ts += __expf(sc[i] - nm);
        ts += __shfl_xor(ts, 16);
        ts += __shfl_xor(ts, 32);
        lrow = lrow * __expf(mrow - nm) + ts;
        mrow = nm;
    }
    const float inv_l = 1.f / lrow;

    // ---------------- pass B: split scores -> p, attn store, PV ------------
    f32x4 cacc[4];
#pragma unroll
    for (int dt = 0; dt < 4; ++dt) cacc[dt] = (f32x4){0.f, 0.f, 0.f, 0.f};
    float* attn_bh = attn + (size_t)(b * H + h) * S * S;

    for (int kt = 0; kt < S / 64; ++kt) {
        const int k0 = kt * 64;
        __syncthreads();
        gl16(KhT + (size_t)(k0 + rd) * 1024 + jo * 8, &Khs[w * 512]);
        gl16(KlT + (size_t)(k0 + rd) * 1024 + jo * 8, &Kls[w * 512]);
        gl16(VtT + (size_t)rd * 2048 + k0 + jo * 8,  &Vts[w * 512]);
        __syncthreads();

        float bias_r[4][4];
#pragma unroll
        for (int st = 0; st < 4; ++st) {
            int4 mv = *(const int4*)&maskg[b * S + k0 + st * 16 + (lane >> 4) * 4];
            bias_r[st][0] = mv.x ? 0.f : -1e9f;
            bias_r[st][1] = mv.y ? 0.f : -1e9f;
            bias_r[st][2] = mv.z ? 0.f : -1e9f;
            bias_r[st][3] = mv.w ? 0.f : -1e9f;
        }

        f32x4 sacc[4];
#pragma unroll
        for (int st = 0; st < 4; ++st) sacc[st] = (f32x4){0.f, 0.f, 0.f, 0.f};
#pragma unroll
        for (int st = 0; st < 4; ++st) {
            int r = st * 16 + q;
#pragma unroll
            for (int dh = 0; dh < 2; ++dh) {
                bf8 kf = *(const bf8*)&Khs[r * 64 + ((dh * 32 + kg) ^ ((r & 7) << 3))];
                bf8 lf = *(const bf8*)&Kls[r * 64 + ((dh * 32 + kg) ^ ((r & 7) << 3))];
                sacc[st] = __builtin_amdgcn_mfma_f32_16x16x32_bf16(kf, qh[dh], sacc[st], 0, 0, 0);
                sacc[st] = __builtin_amdgcn_mfma_f32_16x16x32_bf16(kf, ql[dh], sacc[st], 0, 0, 0);
                sacc[st] = __builtin_amdgcn_mfma_f32_16x16x32_bf16(lf, qh[dh], sacc[st], 0, 0, 0);
            }
        }
        // p = exp(s-m)/l ; fp32 direct store + bf16 pack for PV
#pragma unroll
        for (int st = 0; st < 4; ++st) {
            float pv[4];
#pragma unroll
            for (int rr = 0; rr < 4; ++rr)
                pv[rr] = __expf(sacc[st][rr] * scale + bias_r[st][rr] - mrow) * inv_l;
            float4 f4 = {pv[0], pv[1], pv[2], pv[3]};
            *(float4*)&attn_bh[(size_t)(q0 + w * 16 + q) * S + k0 + st * 16 + (lane >> 4) * 4] = f4;
#pragma unroll
            for (int rp = 0; rp < 2; ++rp) {
                int key = st * 16 + (lane >> 4) * 4 + rp * 2;
                unsigned int pk = (unsigned int)f2bf_rne(pv[rp * 2]) |
                                  ((unsigned int)f2bf_rne(pv[rp * 2 + 1]) << 16);
                *(unsigned int*)&Pus[w][q * 64 + (key ^ ((q & 7) << 3))] = pk;
            }
        }
        // PV: ctx[q][d] += P * V   (wave-private Pus, no barrier needed)
        bf8 pa[2];
        pa[0] = *(const bf8*)&Pus[w][q * 64 + ((kg)      ^ ((q & 7) << 3))];
        pa[1] = *(const bf8*)&Pus[w][q * 64 + ((32 + kg) ^ ((q & 7) << 3))];
#pragma unroll
        for (int dt = 0; dt < 4; ++dt) {
            int r = dt * 16 + q;
#pragma unroll
            for (int kc2 = 0; kc2 < 2; ++kc2) {
                bf8 vf = *(const bf8*)&Vts[r * 64 + ((kc2 * 32 + kg) ^ ((r & 7) << 3))];
                cacc[dt] = __builtin_amdgcn_mfma_f32_16x16x32_bf16(pa[kc2], vf, cacc[dt], 0, 0, 0);
            }
        }
    }

    // ctx (bf16, layout [B*S][D] head-major cols)
#pragma unroll
    for (int dt = 0; dt < 4; ++dt)
#pragma unroll
        for (int rr = 0; rr < 4; ++rr) {
            int qq = q0 + w * 16 + 4 * (lane >> 4) + rr;
            ctx[(size_t)(b * S + qq) * D + h * DK + dt * 16 + (lane & 15)] =
                f2bf_rne(cacc[dt][rr]);
        }
}

// ---------------------------------------------------------------------------
extern "C" void kernel_launch(void* const* d_in, const int* in_sizes, int n_in,
                              void* d_out, int out_size, void* d_ws, size_t ws_size,
                              hipStream_t stream)
{
    const float* query = (const float*)d_in[0];
    const float* key   = (const float*)d_in[1];
    const float* value = (const float*)d_in[2];
    const int*   mask  = (const int*)d_in[3];
    const float* w_q   = (const float*)d_in[4];
    const float* w_k   = (const float*)d_in[5];
    const float* w_v   = (const float*)d_in[6];
    const float* w_o   = (const float*)d_in[7];
    const float* b_o   = (const float*)d_in[8];

    float* out  = (float*)d_out;                       // B*S*D
    float* attn = out + (size_t)B * S * D;             // B*H*S*S

    const size_t NE = (size_t)B * S * D;               // 4M elems
    const size_t WE = (size_t)D * D;                   // 1M elems
    unsigned short* Qh = (unsigned short*)d_ws;
    unsigned short* Ql = Qh + NE;
    unsigned short* Kh = Ql + NE;
    unsigned short* Kl = Kh + NE;
    unsigned short* Vt = Kl + NE;                      // [B][D][S] bf16
    unsigned short* Cb = Vt + NE;                      // ctx bf16  (48 MB so far)
    unsigned short* Xh = Cb + NE;                      // preconv X hi
    unsigned short* Xl = Xh + NE;                      // preconv X lo
    unsigned short* Wh = Xl + NE;                      // preconv W hi
    unsigned short* Wl = Wh + WE;                      // preconv W lo

    const size_t need_full = (size_t)(6 * NE + 2 * NE + 2 * WE) * 2;   // 68 MB

    const dim3 blk(256);
    const dim3 ggrid(D / 64, (B * S) / 128);           // (16, 32)
    const dim3 agrid(S / 128, H, B);                   // (16, 16, 2)

    if (ws_size >= need_full) {
        const int n8x = (int)(NE / 8), n8w = (int)(WE / 8);
        const dim3 cgx((n8x + 255) / 256), cgw((n8w + 255) / 256);

        conv_split_k<<<cgx, blk, 0, stream>>>(query, Xh, Xl, n8x);
        conv_split_k<<<cgw, blk, 0, stream>>>(w_q, Wh, Wl, n8w);
        gemm_bf<true, 1><<<ggrid, blk, 0, stream>>>(Xh, Xl, Wh, Wl, nullptr, Qh, Ql);

        conv_split_k<<<cgx, blk, 0, stream>>>(key, Xh, Xl, n8x);
        conv_split_k<<<cgw, blk, 0, stream>>>(w_k, Wh, Wl, n8w);
        gemm_bf<true, 1><<<ggrid, blk, 0, stream>>>(Xh, Xl, Wh, Wl, nullptr, Kh, Kl);

        conv_hi_k<<<cgx, blk, 0, stream>>>(value, Xh, n8x);
        conv_hi_k<<<cgw, blk, 0, stream>>>(w_v, Wh, n8w);
        gemm_bf<false, 2><<<ggrid, blk, 0, stream>>>(Xh, nullptr, Wh, nullptr, nullptr, Vt, nullptr);

        conv_hi_k<<<cgw, blk, 0, stream>>>(w_o, Wh, n8w);

        attn_mfma2<<<agrid, dim3(512), 0, stream>>>(Qh, Ql, Kh, Kl, Vt, mask, attn, Cb);

        gemm_bf<false, 0><<<ggrid, blk, 0, stream>>>(Cb, nullptr, Wh, nullptr, b_o, out, nullptr);
    } else {
        // 48 MB fallback: round-2 verified GEMMs + new attention kernel
        gemm_mfma<1, true,  false><<<ggrid, blk, 0, stream>>>(query, w_q, nullptr, Qh, Ql);
        gemm_mfma<1, true,  false><<<ggrid, blk, 0, stream>>>(key,   w_k, nullptr, Kh, Kl);
        gemm_mfma<2, false, false><<<ggrid, blk, 0, stream>>>(value, w_v, nullptr, Vt, nullptr);

        attn_mfma2<<<agrid, dim3(512), 0, stream>>>(Qh, Ql, Kh, Kl, Vt, mask, attn, Cb);

        gemm_mfma<0, false, true><<<ggrid, blk, 0, stream>>>(Cb, w_o, b_o, out, nullptr);
    }
}